// Round 10
// baseline (405.601 us; speedup 1.0000x reference)
//
#include <hip/hip_runtime.h>
#include <cstdint>
#include <cstddef>

// ---------- types / helpers ----------
typedef float  f32x4  __attribute__((ext_vector_type(4)));
typedef float  f32x2  __attribute__((ext_vector_type(2)));

__device__ __forceinline__ unsigned int f2fp8x4(float a, float b, float c, float d) {
  int v = __builtin_amdgcn_cvt_pk_fp8_f32(a, b, 0, false);
  v = __builtin_amdgcn_cvt_pk_fp8_f32(c, d, v, true);
  return (unsigned int)v;
}
__device__ __forceinline__ unsigned char f2fp8(float f) {
  return (unsigned char)(__builtin_amdgcn_cvt_pk_fp8_f32(f, f, 0, false) & 0xff);
}
__device__ __forceinline__ void fp8x8_to_f32(uint2 d, float* f) {
  f32x2 a = __builtin_amdgcn_cvt_pk_f32_fp8((int)d.x, false);
  f32x2 b = __builtin_amdgcn_cvt_pk_f32_fp8((int)d.x, true);
  f32x2 c = __builtin_amdgcn_cvt_pk_f32_fp8((int)d.y, false);
  f32x2 e = __builtin_amdgcn_cvt_pk_f32_fp8((int)d.y, true);
  f[0] = a.x; f[1] = a.y; f[2] = b.x; f[3] = b.y;
  f[4] = c.x; f[5] = c.y; f[6] = e.x; f[7] = e.y;
}
__device__ __forceinline__ void fp8x4_to_f32(unsigned int d, float* f) {
  f32x2 a = __builtin_amdgcn_cvt_pk_f32_fp8((int)d, false);
  f32x2 b = __builtin_amdgcn_cvt_pk_f32_fp8((int)d, true);
  f[0] = a.x; f[1] = a.y; f[2] = b.x; f[3] = b.y;
}
__device__ __forceinline__ void fp8x16_to_f32(uint4 d, float* f) {
  uint2 lo; lo.x = d.x; lo.y = d.y;
  uint2 hi; hi.x = d.z; hi.y = d.w;
  fp8x8_to_f32(lo, f);
  fp8x8_to_f32(hi, f + 8);
}

// async global->LDS, 16B per lane. LDS dest must be lane-contiguous in wave order.
__device__ __forceinline__ void async_copy16(const void* g, void* l) {
  __builtin_amdgcn_global_load_lds(
      (const __attribute__((address_space(1))) unsigned int*)g,
      (__attribute__((address_space(3))) unsigned int*)l, 16, 0, 0);
}

#define NN 50000
#define MPAD 50048       // 391 * 128
#define SCAN_BLOCKS 196  // ceil(50000/256); 196*256=50176 >= MPAD

// prep block ranges: X (6256) + W1 (32) + W2 (16) + W3 (4)
#define XB_BLOCKS 6256   // MPAD*512/16/256
#define WB_BLOCKS 52

#define CNT_BLOCKS 512   // low-residency count: 2 blocks/CU, 8 atomics in flight/thread
#define CNT_GS (CNT_BLOCKS * 256)
#define GEMM1_BLOCKS 782 // 391 m-tiles x 2 n-tiles

// ---------- prep: pure streaming X,W -> fp8 (transposed W); zero cnt + gbar counter ----------
__global__ __launch_bounds__(256) void gcn_prep_k(
    const float* __restrict__ X, unsigned char* __restrict__ x8,
    const float* __restrict__ W1, const float* __restrict__ W2,
    const float* __restrict__ W3,
    unsigned char* __restrict__ W1T8, unsigned char* __restrict__ W2T8,
    unsigned char* __restrict__ W3T8, int* __restrict__ cnt, int* __restrict__ bar) {
  int b = blockIdx.x;
  if (b < SCAN_BLOCKS) {
    int ii = b * 256 + threadIdx.x;
    if (ii < NN) cnt[ii] = 0;   // safe: count atomics run in the NEXT dispatch
  }
  if (b == 0 && threadIdx.x < 8) bar[threadIdx.x] = 0;
  if (b < XB_BLOCKS) {
    // X [NN x 512] f32 -> x8 [MPAD x 512] fp8, 16 elems/thread
    int idx16 = (b * 256 + threadIdx.x) * 16;
    int row = idx16 >> 9;
    uint4 o;
    if (row < NN) {
      const float* s = &X[idx16];
      float4 v0 = *(const float4*)s;
      float4 v1 = *(const float4*)(s + 4);
      float4 v2 = *(const float4*)(s + 8);
      float4 v3 = *(const float4*)(s + 12);
      o.x = f2fp8x4(v0.x, v0.y, v0.z, v0.w);
      o.y = f2fp8x4(v1.x, v1.y, v1.z, v1.w);
      o.z = f2fp8x4(v2.x, v2.y, v2.z, v2.w);
      o.w = f2fp8x4(v3.x, v3.y, v3.z, v3.w);
    } else {
      o = uint4{0, 0, 0, 0};
    }
    *(uint4*)&x8[idx16] = o;
  } else {
    int wb = b - XB_BLOCKS;
    if (wb < 32) {
      // W1 [512x256] -> W1T8 [256x512] fp8, 16/thread
      int idx16 = (wb * 256 + threadIdx.x) * 16;
      int n = idx16 >> 9;
      float f[16];
#pragma unroll
      for (int j = 0; j < 16; j++) f[j] = W1[(size_t)((idx16 & 511) + j) * 256 + n];
      uint4 o;
      o.x = f2fp8x4(f[0], f[1], f[2], f[3]);
      o.y = f2fp8x4(f[4], f[5], f[6], f[7]);
      o.z = f2fp8x4(f[8], f[9], f[10], f[11]);
      o.w = f2fp8x4(f[12], f[13], f[14], f[15]);
      *(uint4*)&W1T8[idx16] = o;
    } else if (wb < 48) {
      // W2 [256x256] -> W2T8 [256x256] fp8
      int idx16 = ((wb - 32) * 256 + threadIdx.x) * 16;
      int n = idx16 >> 8;
      float f[16];
#pragma unroll
      for (int j = 0; j < 16; j++) f[j] = W2[(size_t)((idx16 & 255) + j) * 256 + n];
      uint4 o;
      o.x = f2fp8x4(f[0], f[1], f[2], f[3]);
      o.y = f2fp8x4(f[4], f[5], f[6], f[7]);
      o.z = f2fp8x4(f[8], f[9], f[10], f[11]);
      o.w = f2fp8x4(f[12], f[13], f[14], f[15]);
      *(uint4*)&W2T8[idx16] = o;
    } else {
      // W3 [256x64] -> W3T8 [64x256] fp8
      int idx16 = ((wb - 48) * 256 + threadIdx.x) * 16;
      int n = idx16 >> 8;
      float f[16];
#pragma unroll
      for (int j = 0; j < 16; j++) f[j] = W3[(size_t)((idx16 & 255) + j) * 64 + n];
      uint4 o;
      o.x = f2fp8x4(f[0], f[1], f[2], f[3]);
      o.y = f2fp8x4(f[4], f[5], f[6], f[7]);
      o.z = f2fp8x4(f[8], f[9], f[10], f[11]);
      o.w = f2fp8x4(f[12], f[13], f[14], f[15]);
      *(uint4*)&W3T8[idx16] = o;
    }
  }
}

// ---------- heterogeneous: low-residency count (512 blocks, 8 atomics/thread in flight)
// + layer-1 GEMM (782 blocks). Count occupies only ~2 block-slots/CU, so GEMM blocks
// co-schedule from t=0 -> true concurrency (R8's 3125 tiny blocks filled every slot
// and serialized the phases).
__global__ __launch_bounds__(256) void gcn_count_gemm1_k(
    const unsigned char* __restrict__ A8,   // x8 [MPAD x 512]
    const unsigned char* __restrict__ Bt8,  // W1T8 [256 x 512]
    unsigned char* __restrict__ C8,         // h8 [MPAD x 256] (unscaled)
    const int* __restrict__ dst, int* __restrict__ cnt, int* __restrict__ rank, int E) {
  __shared__ __align__(16) unsigned char lds_a[2][128 * 32];
  __shared__ __align__(16) unsigned char lds_b[2][128 * 32];
  int b = blockIdx.x;
  if (b < CNT_BLOCKS) {
    // 8 independent atomic+store pairs per chunk -> 8 outstanding per thread
    int e = b * 256 + threadIdx.x;
    for (; e < E; ) {
      int ee[8]; bool v[8]; int d[8];
#pragma unroll
      for (int k = 0; k < 8; k++) {
        ee[k] = e + k * CNT_GS;
        v[k] = ee[k] < E;
        d[k] = v[k] ? dst[ee[k]] : 0;
      }
      int r[8];
#pragma unroll
      for (int k = 0; k < 8; k++)
        if (v[k]) r[k] = atomicAdd(&cnt[d[k]], 1);
#pragma unroll
      for (int k = 0; k < 8; k++)
        if (v[k]) rank[ee[k]] = r[k];
      e += 8 * CNT_GS;
    }
    return;
  }
  int bg = b - CNT_BLOCKS;
  const int K = 512, N = 256;
  const int t = threadIdx.x;
  const int wave = t >> 6, lane = t & 63;
  const int wr = wave >> 1, wc = wave & 1;
  const int quad = lane >> 4, lrow = lane & 15;
  const int m0 = (bg >> 1) * 128;
  const int n0 = (bg & 1) * 128;

  f32x4 acc[4][4] = {};

  auto stage = [&](int buf, int k0) {
    int r = t >> 1, c = (t & 1) * 16;
    async_copy16(&A8[(size_t)(m0 + r) * K + k0 + c], &lds_a[buf][t * 16]);
    async_copy16(&Bt8[(size_t)(n0 + r) * K + k0 + c], &lds_b[buf][t * 16]);
  };
  auto compute = [&](int buf) {
    long af[4], bfr[4];
#pragma unroll
    for (int mt = 0; mt < 4; mt++)
      af[mt] = *(const long*)&lds_a[buf][(wr * 64 + mt * 16 + lrow) * 32 + quad * 8];
#pragma unroll
    for (int nt = 0; nt < 4; nt++)
      bfr[nt] = *(const long*)&lds_b[buf][(wc * 64 + nt * 16 + lrow) * 32 + quad * 8];
#pragma unroll
    for (int mt = 0; mt < 4; mt++)
#pragma unroll
      for (int nt = 0; nt < 4; nt++)
        acc[mt][nt] = __builtin_amdgcn_mfma_f32_16x16x32_fp8_fp8(af[mt], bfr[nt], acc[mt][nt], 0, 0, 0);
  };

  stage(0, 0);
  int curb = 0;
  int k0 = 0;
  for (; k0 + 32 < K; k0 += 32) {
    stage(curb ^ 1, k0 + 32);                         // prefetch next tile
    asm volatile("s_waitcnt vmcnt(2)" ::: "memory");  // wait ONLY current tile's loads
    __builtin_amdgcn_s_barrier();
    asm volatile("" ::: "memory");
    compute(curb);
    asm volatile("" ::: "memory");
    __builtin_amdgcn_s_barrier();
    curb ^= 1;
  }
  asm volatile("s_waitcnt vmcnt(0)" ::: "memory");
  __builtin_amdgcn_s_barrier();
  asm volatile("" ::: "memory");
  compute(curb);

#pragma unroll
  for (int mt = 0; mt < 4; mt++)
#pragma unroll
    for (int nt = 0; nt < 4; nt++)
#pragma unroll
      for (int r = 0; r < 4; r++) {
        int row = m0 + wr * 64 + mt * 16 + quad * 4 + r;
        int col = n0 + wc * 64 + nt * 16 + lrow;
        C8[(size_t)row * N + col] = f2fp8(acc[mt][nt][r]);
      }
}

// ---------- fused scan: one kernel, 196 co-resident blocks, ONE grid barrier ----------
__device__ __forceinline__ void gbar(int* bar, int target) {
  __syncthreads();
  if (threadIdx.x == 0) {
    __hip_atomic_fetch_add(bar, 1, __ATOMIC_ACQ_REL, __HIP_MEMORY_SCOPE_AGENT);
    while (__hip_atomic_load(bar, __ATOMIC_ACQUIRE, __HIP_MEMORY_SCOPE_AGENT) < target)
      __builtin_amdgcn_s_sleep(2);
  }
  __syncthreads();
}

__global__ __launch_bounds__(256) void gcn_scan_k(
    const int* __restrict__ cnt, int* __restrict__ rs, float* __restrict__ dinv,
    int* __restrict__ bsum, int* __restrict__ bar, int E) {
  __shared__ int sb[256];
  __shared__ int sc[256];
  const int t = threadIdx.x, b = blockIdx.x;
  const int i = b * 256 + t;
  int v = (i < NN) ? cnt[i] : 0;
  sb[t] = v;
  __syncthreads();
  for (int off = 1; off < 256; off <<= 1) {
    int x = (t >= off) ? sb[t - off] : 0;
    __syncthreads();
    sb[t] += x;
    __syncthreads();
  }
  if (t == 255) bsum[b] = sb[255];
  gbar(bar, SCAN_BLOCKS);                 // all block sums visible
  // each block redundantly scans the 196 block sums
  int w = (t < SCAN_BLOCKS) ? bsum[t] : 0;
  sc[t] = w;
  __syncthreads();
  for (int off = 1; off < 256; off <<= 1) {
    int y = (t >= off) ? sc[t - off] : 0;
    __syncthreads();
    sc[t] += y;
    __syncthreads();
  }
  int base = sc[b] - bsum[b];             // exclusive prefix of blockSums
  if (i < NN) {
    rs[i] = base + sb[t] - v;
    dinv[i] = rsqrtf(1.0f + (float)v);
  } else if (i < MPAD) {
    dinv[i] = 0.0f;   // pad rows
  }
  if (i == 0) rs[NN] = E;
}

// ---------- scatter: atomic-free (rank precomputed), src-only payload ----------
__global__ void gcn_scatter_k(const int* __restrict__ src, const int* __restrict__ dst,
                              const int* __restrict__ rank, const int* __restrict__ rs,
                              int* __restrict__ e4, int E) {
  int e = blockIdx.x * 256 + threadIdx.x;
  if (e < E) {
    int d = dst[e];
    e4[rs[d] + rank[e]] = src[e];
  }
}

// ---------- fp8 GEMM, 2-phase double-buffered, epilogue scales rows by dinv (layer 2) ----------
template<int BN, int WTN>
__global__ __launch_bounds__(256) void gcn_gemm_f8_db_k(
    const unsigned char* __restrict__ A8,   // [MPAD x K] fp8
    const unsigned char* __restrict__ Bt8,  // [N x K]    fp8
    const float* __restrict__ dinv,         // [MPAD]
    unsigned char* __restrict__ C8,         // [MPAD x N] fp8 (pre-scaled by dinv[row])
    int K, int N) {
  static_assert(BN == 128, "db kernel assumes uniform 2 global_load_lds per thread");
  __shared__ __align__(16) unsigned char lds_a[2][128 * 32];
  __shared__ __align__(16) unsigned char lds_b[2][BN * 32];
  const int t = threadIdx.x;
  const int wave = t >> 6, lane = t & 63;
  const int wr = wave >> 1, wc = wave & 1;
  const int quad = lane >> 4, lrow = lane & 15;
  const int m0 = blockIdx.x * 128;
  const int n0 = blockIdx.y * BN;

  f32x4 acc[4][WTN] = {};

  auto stage = [&](int buf, int k0) {
    int r = t >> 1, c = (t & 1) * 16;
    async_copy16(&A8[(size_t)(m0 + r) * K + k0 + c], &lds_a[buf][t * 16]);
    async_copy16(&Bt8[(size_t)(n0 + r) * K + k0 + c], &lds_b[buf][t * 16]);
  };
  auto compute = [&](int buf) {
    long af[4], bfr[WTN];
#pragma unroll
    for (int mt = 0; mt < 4; mt++)
      af[mt] = *(const long*)&lds_a[buf][(wr * 64 + mt * 16 + lrow) * 32 + quad * 8];
#pragma unroll
    for (int nt = 0; nt < WTN; nt++)
      bfr[nt] = *(const long*)&lds_b[buf][(wc * (BN / 2) + nt * 16 + lrow) * 32 + quad * 8];
#pragma unroll
    for (int mt = 0; mt < 4; mt++)
#pragma unroll
      for (int nt = 0; nt < WTN; nt++)
        acc[mt][nt] = __builtin_amdgcn_mfma_f32_16x16x32_fp8_fp8(af[mt], bfr[nt], acc[mt][nt], 0, 0, 0);
  };

  stage(0, 0);
  int curb = 0;
  int k0 = 0;
  for (; k0 + 32 < K; k0 += 32) {
    stage(curb ^ 1, k0 + 32);                         // prefetch next tile
    asm volatile("s_waitcnt vmcnt(2)" ::: "memory");  // wait ONLY current tile's loads
    __builtin_amdgcn_s_barrier();
    asm volatile("" ::: "memory");
    compute(curb);
    asm volatile("" ::: "memory");
    __builtin_amdgcn_s_barrier();
    curb ^= 1;
  }
  asm volatile("s_waitcnt vmcnt(0)" ::: "memory");
  __builtin_amdgcn_s_barrier();
  asm volatile("" ::: "memory");
  compute(curb);

#pragma unroll
  for (int mt = 0; mt < 4; mt++)
#pragma unroll
    for (int r = 0; r < 4; r++) {
      int row = m0 + wr * 64 + mt * 16 + quad * 4 + r;
      float dv = dinv[row];
#pragma unroll
      for (int nt = 0; nt < WTN; nt++) {
        int col = n0 + wc * (BN / 2) + nt * 16 + lrow;
        C8[(size_t)row * N + col] = f2fp8(acc[mt][nt][r] * dv);
      }
    }
}

// ---------- fp8 GEMM, single-buffered (layer 3: BN=64), dinv epilogue ----------
template<int BN, int WTN>
__global__ __launch_bounds__(256) void gcn_gemm_f8_s_k(
    const unsigned char* __restrict__ A8, const unsigned char* __restrict__ Bt8,
    const float* __restrict__ dinv, unsigned char* __restrict__ C8, int K, int N) {
  __shared__ __align__(16) unsigned char lds_a[128 * 32];
  __shared__ __align__(16) unsigned char lds_b[BN * 32];
  const int t = threadIdx.x;
  const int wave = t >> 6, lane = t & 63;
  const int wr = wave >> 1, wc = wave & 1;
  const int quad = lane >> 4, lrow = lane & 15;
  const int m0 = blockIdx.x * 128;
  const int n0 = blockIdx.y * BN;

  f32x4 acc[4][WTN] = {};

  for (int k0 = 0; k0 < K; k0 += 32) {
    __syncthreads();
    {
      int r = t >> 1, c = (t & 1) * 16;
      async_copy16(&A8[(size_t)(m0 + r) * K + k0 + c], &lds_a[t * 16]);
    }
    for (int q = t; q < BN * 2; q += 256) {
      int r = q >> 1, c = (q & 1) * 16;
      async_copy16(&Bt8[(size_t)(n0 + r) * K + k0 + c], &lds_b[q * 16]);
    }
    __syncthreads();
    long af[4], bfr[WTN];
#pragma unroll
    for (int mt = 0; mt < 4; mt++)
      af[mt] = *(const long*)&lds_a[(wr * 64 + mt * 16 + lrow) * 32 + quad * 8];
#pragma unroll
    for (int nt = 0; nt < WTN; nt++)
      bfr[nt] = *(const long*)&lds_b[(wc * (BN / 2) + nt * 16 + lrow) * 32 + quad * 8];
#pragma unroll
    for (int mt = 0; mt < 4; mt++)
#pragma unroll
      for (int nt = 0; nt < WTN; nt++)
        acc[mt][nt] = __builtin_amdgcn_mfma_f32_16x16x32_fp8_fp8(af[mt], bfr[nt], acc[mt][nt], 0, 0, 0);
  }

#pragma unroll
  for (int mt = 0; mt < 4; mt++)
#pragma unroll
    for (int r = 0; r < 4; r++) {
      int row = m0 + wr * 64 + mt * 16 + quad * 4 + r;
      float dv = dinv[row];
#pragma unroll
      for (int nt = 0; nt < WTN; nt++) {
        int col = n0 + wc * (BN / 2) + nt * 16 + lrow;
        C8[(size_t)row * N + col] = f2fp8(acc[mt][nt][r] * dv);
      }
    }
}

// ---------- aggregation (D=256), 4 gathers in flight per 16-lane group (proven depth) ----------
// WSRC=1 (layer 1): h8 unscaled -> per-edge weight dinv[src], self weight dinv[i].
// WSRC=0 (layer 2): rows are g = dinv*h -> weight 1, self weight 1.
// Both finish with out = relu(dinv_i * sum + bias).
template<int D, int WSRC>
__global__ __launch_bounds__(256) void gcn_agg_relu_k(
    const unsigned char* __restrict__ g8, const int* __restrict__ rs,
    const int* __restrict__ e4, const float* __restrict__ dinv,
    const float* __restrict__ bias, unsigned char* __restrict__ out8, int nNodes) {
  int wave = threadIdx.x >> 6, lane = threadIdx.x & 63;
  int i = blockIdx.x * 4 + wave;
  if (i >= nNodes) return;
  int q = lane >> 4, sub = lane & 15;
  int f0 = sub * 16;                       // 16 features per lane
  float di = dinv[i];
  uint4 dself = *(const uint4*)&g8[(size_t)i * D + f0];
  float sv[16];
  fp8x16_to_f32(dself, sv);
  float wself = (q == 0) ? (WSRC ? di : 1.0f) : 0.0f;
  float acc[16];
#pragma unroll
  for (int j = 0; j < 16; j++) acc[j] = sv[j] * wself;

  int e0 = rs[i], e1 = rs[i + 1];
  int nIter = (e1 - e0 + 15) >> 4;         // 16 edges per iteration (4 per group)
  int e = e0 + q;
  for (int k = 0; k < nIter; k++) {
    int idx[4]; float w[4];
#pragma unroll
    for (int u = 0; u < 4; u++) {
      int ee = e + 4 * u;
      bool v = ee < e1;
      idx[u] = v ? e4[ee] : 0;
      w[u] = v ? (WSRC ? dinv[idx[u]] : 1.0f) : 0.0f;
    }
    uint4 d0 = *(const uint4*)&g8[(size_t)idx[0] * D + f0];
    uint4 d1 = *(const uint4*)&g8[(size_t)idx[1] * D + f0];
    uint4 d2 = *(const uint4*)&g8[(size_t)idx[2] * D + f0];
    uint4 d3 = *(const uint4*)&g8[(size_t)idx[3] * D + f0];
    float r[16];
    fp8x16_to_f32(d0, r);
#pragma unroll
    for (int j = 0; j < 16; j++) acc[j] += r[j] * w[0];
    fp8x16_to_f32(d1, r);
#pragma unroll
    for (int j = 0; j < 16; j++) acc[j] += r[j] * w[1];
    fp8x16_to_f32(d2, r);
#pragma unroll
    for (int j = 0; j < 16; j++) acc[j] += r[j] * w[2];
    fp8x16_to_f32(d3, r);
#pragma unroll
    for (int j = 0; j < 16; j++) acc[j] += r[j] * w[3];
    e += 16;
  }
#pragma unroll
  for (int j = 0; j < 16; j++) {
    acc[j] += __shfl_xor(acc[j], 16);
    acc[j] += __shfl_xor(acc[j], 32);
  }
  if (q == 0) {
    float4 bb0 = *(const float4*)&bias[f0];
    float4 bb1 = *(const float4*)&bias[f0 + 4];
    float4 bb2 = *(const float4*)&bias[f0 + 8];
    float4 bb3 = *(const float4*)&bias[f0 + 12];
    float bv[16] = {bb0.x, bb0.y, bb0.z, bb0.w, bb1.x, bb1.y, bb1.z, bb1.w,
                    bb2.x, bb2.y, bb2.z, bb2.w, bb3.x, bb3.y, bb3.z, bb3.w};
    float r[16];
#pragma unroll
    for (int j = 0; j < 16; j++) {
      float z = di * acc[j] + bv[j];
      r[j] = z > 0.0f ? z : 0.0f;
    }
    uint4 o;
    o.x = f2fp8x4(r[0], r[1], r[2], r[3]);
    o.y = f2fp8x4(r[4], r[5], r[6], r[7]);
    o.z = f2fp8x4(r[8], r[9], r[10], r[11]);
    o.w = f2fp8x4(r[12], r[13], r[14], r[15]);
    *(uint4*)&out8[(size_t)i * D + f0] = o;
  }
}

// final layer: D=64 g-rows; 2 gathers in flight per 16-lane group (proven depth)
__global__ __launch_bounds__(256) void gcn_agg_final_k(
    const unsigned char* __restrict__ g8, const int* __restrict__ rs,
    const int* __restrict__ e4, const float* __restrict__ dinv,
    const float* __restrict__ bias, float* __restrict__ out, int nNodes) {
  int wave = threadIdx.x >> 6, lane = threadIdx.x & 63;
  int i = blockIdx.x * 4 + wave;
  if (i >= nNodes) return;
  int qtr = lane >> 4, sub = lane & 15;
  int f0 = sub * 4;
  float di = dinv[i];
  unsigned int dself = *(const unsigned int*)&g8[(size_t)i * 64 + f0];
  float sv[4];
  fp8x4_to_f32(dself, sv);
  float wself = (qtr == 0) ? 1.0f : 0.0f;
  float acc[4];
#pragma unroll
  for (int j = 0; j < 4; j++) acc[j] = sv[j] * wself;

  int e0 = rs[i], e1 = rs[i + 1];
  int nIter = (e1 - e0 + 7) >> 3;
  int e = e0 + qtr;
  for (int k = 0; k < nIter; k++) {
    int idx[2]; float w[2];
#pragma unroll
    for (int u = 0; u < 2; u++) {
      int ee = e + 4 * u;
      bool v = ee < e1;
      idx[u] = v ? e4[ee] : 0;
      w[u] = v ? 1.0f : 0.0f;
    }
    unsigned int d0 = *(const unsigned int*)&g8[(size_t)idx[0] * 64 + f0];
    unsigned int d1 = *(const unsigned int*)&g8[(size_t)idx[1] * 64 + f0];
    float r0[4], r1[4];
    fp8x4_to_f32(d0, r0); fp8x4_to_f32(d1, r1);
#pragma unroll
    for (int j = 0; j < 4; j++)
      acc[j] += r0[j] * w[0] + r1[j] * w[1];
    e += 8;
  }
#pragma unroll
  for (int j = 0; j < 4; j++) {
    acc[j] += __shfl_xor(acc[j], 16);
    acc[j] += __shfl_xor(acc[j], 32);
    acc[j] = di * acc[j] + bias[f0 + j];
  }
  // softmax over 64 features (16 lanes x 4 regs; all lanes hold full sums)
  float m = fmaxf(fmaxf(acc[0], acc[1]), fmaxf(acc[2], acc[3]));
#pragma unroll
  for (int off = 8; off > 0; off >>= 1) m = fmaxf(m, __shfl_xor(m, off));
  float ex[4], s = 0.0f;
#pragma unroll
  for (int j = 0; j < 4; j++) { ex[j] = __expf(acc[j] - m); s += ex[j]; }
#pragma unroll
  for (int off = 8; off > 0; off >>= 1) s += __shfl_xor(s, off);
  float rcs = 1.0f / s;
  float p[4], s2 = 0.0f;
#pragma unroll
  for (int j = 0; j < 4; j++) { p[j] = ex[j] * rcs; s2 += __expf(p[j]); }
#pragma unroll
  for (int off = 8; off > 0; off >>= 1) s2 += __shfl_xor(s2, off);
  float ls = __logf(s2);
  if (qtr == 0) {
    float4 o; o.x = p[0] - ls; o.y = p[1] - ls; o.z = p[2] - ls; o.w = p[3] - ls;
    *(float4*)&out[(size_t)i * 64 + f0] = o;
  }
}

// ---------- launch ----------
extern "C" void kernel_launch(void* const* d_in, const int* in_sizes, int n_in,
                              void* d_out, int out_size, void* d_ws, size_t ws_size,
                              hipStream_t stream) {
  const float* x    = (const float*)d_in[0];
  const int*   eidx = (const int*)d_in[1];
  const float* W1   = (const float*)d_in[2];
  const float* b1   = (const float*)d_in[3];
  const float* W2   = (const float*)d_in[4];
  const float* b2   = (const float*)d_in[5];
  const float* W3   = (const float*)d_in[6];
  const float* b3   = (const float*)d_in[7];
  float* out = (float*)d_out;

  const int E = in_sizes[1] / 2;            // 800000
  const int* src = eidx;
  const int* dst = eidx + E;

  char* p = (char*)d_ws;
  auto alloc = [&](size_t bytes) -> void* {
    void* r = (void*)p;
    p += (bytes + 255) & ~(size_t)255;
    return r;
  };
  unsigned char*  x8   = (unsigned char*)alloc((size_t)MPAD * 512);
  unsigned char*  g8   = (unsigned char*)alloc((size_t)MPAD * 256);  // gemm out fp8
  unsigned char*  a8   = (unsigned char*)alloc((size_t)MPAD * 256);  // agg out fp8
  unsigned char*  g83  = (unsigned char*)alloc((size_t)MPAD * 64);
  unsigned char*  W1T8 = (unsigned char*)alloc((size_t)256 * 512);
  unsigned char*  W2T8 = (unsigned char*)alloc((size_t)256 * 256);
  unsigned char*  W3T8 = (unsigned char*)alloc((size_t)64 * 256);
  int*   cnt  = (int*)alloc((size_t)NN * 4);
  int*   rs   = (int*)alloc((size_t)(NN + 1) * 4);
  int*   rank = (int*)alloc((size_t)E * 4);
  float* dinv = (float*)alloc((size_t)MPAD * 4);
  int*   e4   = (int*)alloc((size_t)(E + 64) * 4);
  int*   bsum = (int*)alloc((size_t)SCAN_BLOCKS * 4);
  int*   bar  = (int*)alloc((size_t)8 * 4);

  const int EB = (E + 255) / 256;  // 3125
  // 1. prep (pure streaming; zeroes cnt + gbar counter)
  gcn_prep_k<<<XB_BLOCKS + WB_BLOCKS, 256, 0, stream>>>(
      x, x8, W1, W2, W3, W1T8, W2T8, W3T8, cnt, bar);
  // 2. low-residency count + layer-1 GEMM, truly concurrent in one dispatch
  gcn_count_gemm1_k<<<CNT_BLOCKS + GEMM1_BLOCKS, 256, 0, stream>>>(
      x8, W1T8, g8, dst, cnt, rank, E);
  // 3. fused scan (one grid barrier, 196 co-resident blocks)
  gcn_scan_k<<<SCAN_BLOCKS, 256, 0, stream>>>(cnt, rs, dinv, bsum, bar, E);
  // 4. scatter
  gcn_scatter_k<<<EB, 256, 0, stream>>>(src, dst, rank, rs, e4, E);
  // 5. layer 1 aggregation (h unscaled -> per-edge dinv[src] weights)
  gcn_agg_relu_k<256, 1><<<(NN + 3) / 4, 256, 0, stream>>>(g8, rs, e4, dinv, b1, a8, NN);
  const int MB = MPAD / 128;  // 391
  // 6-7. layer 2
  gcn_gemm_f8_db_k<128, 4><<<dim3(MB, 2), 256, 0, stream>>>(a8, W2T8, dinv, g8, 256, 256);
  gcn_agg_relu_k<256, 0><<<(NN + 3) / 4, 256, 0, stream>>>(g8, rs, e4, dinv, b2, a8, NN);
  // 8-9. layer 3 + fused softmax/log_softmax
  gcn_gemm_f8_s_k<64, 2><<<dim3(MB, 1), 256, 0, stream>>>(a8, W3T8, dinv, g83, 256, 64);
  gcn_agg_final_k<<<(NN + 3) / 4, 256, 0, stream>>>(g83, rs, e4, dinv, b3, out, NN);

  (void)n_in; (void)out_size; (void)ws_size;
}

// Round 11
// 394.836 us; speedup vs baseline: 1.0273x; 1.0273x over previous
//
#include <hip/hip_runtime.h>
#include <cstdint>
#include <cstddef>

// ---------- types / helpers ----------
typedef float  f32x4  __attribute__((ext_vector_type(4)));
typedef float  f32x2  __attribute__((ext_vector_type(2)));

__device__ __forceinline__ unsigned int f2fp8x4(float a, float b, float c, float d) {
  int v = __builtin_amdgcn_cvt_pk_fp8_f32(a, b, 0, false);
  v = __builtin_amdgcn_cvt_pk_fp8_f32(c, d, v, true);
  return (unsigned int)v;
}
__device__ __forceinline__ unsigned char f2fp8(float f) {
  return (unsigned char)(__builtin_amdgcn_cvt_pk_fp8_f32(f, f, 0, false) & 0xff);
}
__device__ __forceinline__ void fp8x8_to_f32(uint2 d, float* f) {
  f32x2 a = __builtin_amdgcn_cvt_pk_f32_fp8((int)d.x, false);
  f32x2 b = __builtin_amdgcn_cvt_pk_f32_fp8((int)d.x, true);
  f32x2 c = __builtin_amdgcn_cvt_pk_f32_fp8((int)d.y, false);
  f32x2 e = __builtin_amdgcn_cvt_pk_f32_fp8((int)d.y, true);
  f[0] = a.x; f[1] = a.y; f[2] = b.x; f[3] = b.y;
  f[4] = c.x; f[5] = c.y; f[6] = e.x; f[7] = e.y;
}
__device__ __forceinline__ void fp8x4_to_f32(unsigned int d, float* f) {
  f32x2 a = __builtin_amdgcn_cvt_pk_f32_fp8((int)d, false);
  f32x2 b = __builtin_amdgcn_cvt_pk_f32_fp8((int)d, true);
  f[0] = a.x; f[1] = a.y; f[2] = b.x; f[3] = b.y;
}
__device__ __forceinline__ void fp8x16_to_f32(uint4 d, float* f) {
  uint2 lo; lo.x = d.x; lo.y = d.y;
  uint2 hi; hi.x = d.z; hi.y = d.w;
  fp8x8_to_f32(lo, f);
  fp8x8_to_f32(hi, f + 8);
}

// async global->LDS, 16B per lane. LDS dest must be lane-contiguous in wave order.
__device__ __forceinline__ void async_copy16(const void* g, void* l) {
  __builtin_amdgcn_global_load_lds(
      (const __attribute__((address_space(1))) unsigned int*)g,
      (__attribute__((address_space(3))) unsigned int*)l, 16, 0, 0);
}

#define NN 50000
#define MPAD 50048       // 391 * 128
#define SCAN_BLOCKS 196  // ceil(50000/256); 196*256=50176 >= MPAD
#define NREP 8           // one degree-count replica per XCD (blockIdx round-robin)

// prep block ranges: X (6256) + W1 (32) + W2 (16) + W3 (4)
#define XB_BLOCKS 6256   // MPAD*512/16/256
#define WB_BLOCKS 52
#define ZB_BLOCKS 1568   // 196*8 blocks zero the 8 replicas (401408 >= 400000 ints)

#define COUNT_BLOCKS 3125
#define GEMM1_BLOCKS 782 // 391 m-tiles x 2 n-tiles

// ---------- prep: pure streaming X,W -> fp8 (transposed W); zero cnt8 replicas ----------
__global__ __launch_bounds__(256) void gcn_prep_k(
    const float* __restrict__ X, unsigned char* __restrict__ x8,
    const float* __restrict__ W1, const float* __restrict__ W2,
    const float* __restrict__ W3,
    unsigned char* __restrict__ W1T8, unsigned char* __restrict__ W2T8,
    unsigned char* __restrict__ W3T8, int* __restrict__ cnt8) {
  int b = blockIdx.x;
  if (b < ZB_BLOCKS) {
    int ii = b * 256 + threadIdx.x;
    if (ii < NREP * NN) cnt8[ii] = 0;   // safe: count atomics run in the NEXT dispatch
  }
  if (b < XB_BLOCKS) {
    // X [NN x 512] f32 -> x8 [MPAD x 512] fp8, 16 elems/thread
    int idx16 = (b * 256 + threadIdx.x) * 16;
    int row = idx16 >> 9;
    uint4 o;
    if (row < NN) {
      const float* s = &X[idx16];
      float4 v0 = *(const float4*)s;
      float4 v1 = *(const float4*)(s + 4);
      float4 v2 = *(const float4*)(s + 8);
      float4 v3 = *(const float4*)(s + 12);
      o.x = f2fp8x4(v0.x, v0.y, v0.z, v0.w);
      o.y = f2fp8x4(v1.x, v1.y, v1.z, v1.w);
      o.z = f2fp8x4(v2.x, v2.y, v2.z, v2.w);
      o.w = f2fp8x4(v3.x, v3.y, v3.z, v3.w);
    } else {
      o = uint4{0, 0, 0, 0};
    }
    *(uint4*)&x8[idx16] = o;
  } else {
    int wb = b - XB_BLOCKS;
    if (wb < 32) {
      // W1 [512x256] -> W1T8 [256x512] fp8, 16/thread
      int idx16 = (wb * 256 + threadIdx.x) * 16;
      int n = idx16 >> 9;
      float f[16];
#pragma unroll
      for (int j = 0; j < 16; j++) f[j] = W1[(size_t)((idx16 & 511) + j) * 256 + n];
      uint4 o;
      o.x = f2fp8x4(f[0], f[1], f[2], f[3]);
      o.y = f2fp8x4(f[4], f[5], f[6], f[7]);
      o.z = f2fp8x4(f[8], f[9], f[10], f[11]);
      o.w = f2fp8x4(f[12], f[13], f[14], f[15]);
      *(uint4*)&W1T8[idx16] = o;
    } else if (wb < 48) {
      // W2 [256x256] -> W2T8 [256x256] fp8
      int idx16 = ((wb - 32) * 256 + threadIdx.x) * 16;
      int n = idx16 >> 8;
      float f[16];
#pragma unroll
      for (int j = 0; j < 16; j++) f[j] = W2[(size_t)((idx16 & 255) + j) * 256 + n];
      uint4 o;
      o.x = f2fp8x4(f[0], f[1], f[2], f[3]);
      o.y = f2fp8x4(f[4], f[5], f[6], f[7]);
      o.z = f2fp8x4(f[8], f[9], f[10], f[11]);
      o.w = f2fp8x4(f[12], f[13], f[14], f[15]);
      *(uint4*)&W2T8[idx16] = o;
    } else {
      // W3 [256x64] -> W3T8 [64x256] fp8
      int idx16 = ((wb - 48) * 256 + threadIdx.x) * 16;
      int n = idx16 >> 8;
      float f[16];
#pragma unroll
      for (int j = 0; j < 16; j++) f[j] = W3[(size_t)((idx16 & 255) + j) * 64 + n];
      uint4 o;
      o.x = f2fp8x4(f[0], f[1], f[2], f[3]);
      o.y = f2fp8x4(f[4], f[5], f[6], f[7]);
      o.z = f2fp8x4(f[8], f[9], f[10], f[11]);
      o.w = f2fp8x4(f[12], f[13], f[14], f[15]);
      *(uint4*)&W3T8[idx16] = o;
    }
  }
}

// ---------- heterogeneous: XCD-local count (8 replicas) + layer-1 GEMM ----------
// Count block b uses replica b&7. Consecutive blockIdx round-robin across XCDs,
// so each replica's 200KB of lines is touched by ONE XCD -> atomics stay in that
// XCD's L2 (no cross-XCD line-ownership migration = the R8-R10 throttle theory).
// Perf heuristic only: correctness holds for any block->XCD mapping.
__global__ __launch_bounds__(256) void gcn_count_gemm1_k(
    const unsigned char* __restrict__ A8,   // x8 [MPAD x 512]
    const unsigned char* __restrict__ Bt8,  // W1T8 [256 x 512]
    unsigned char* __restrict__ C8,         // h8 [MPAD x 256] (unscaled)
    const int* __restrict__ dst, int* __restrict__ cnt8, int* __restrict__ rank, int E) {
  __shared__ __align__(16) unsigned char lds_a[2][128 * 32];
  __shared__ __align__(16) unsigned char lds_b[2][128 * 32];
  int b = blockIdx.x;
  if (b < COUNT_BLOCKS) {
    int e = b * 256 + threadIdx.x;
    int r = b & (NREP - 1);
    if (e < E) rank[e] = atomicAdd(&cnt8[r * NN + dst[e]], 1);
    return;
  }
  int bg = b - COUNT_BLOCKS;
  const int K = 512, N = 256;
  const int t = threadIdx.x;
  const int wave = t >> 6, lane = t & 63;
  const int wr = wave >> 1, wc = wave & 1;
  const int quad = lane >> 4, lrow = lane & 15;
  const int m0 = (bg >> 1) * 128;
  const int n0 = (bg & 1) * 128;

  f32x4 acc[4][4] = {};

  auto stage = [&](int buf, int k0) {
    int r = t >> 1, c = (t & 1) * 16;
    async_copy16(&A8[(size_t)(m0 + r) * K + k0 + c], &lds_a[buf][t * 16]);
    async_copy16(&Bt8[(size_t)(n0 + r) * K + k0 + c], &lds_b[buf][t * 16]);
  };
  auto compute = [&](int buf) {
    long af[4], bfr[4];
#pragma unroll
    for (int mt = 0; mt < 4; mt++)
      af[mt] = *(const long*)&lds_a[buf][(wr * 64 + mt * 16 + lrow) * 32 + quad * 8];
#pragma unroll
    for (int nt = 0; nt < 4; nt++)
      bfr[nt] = *(const long*)&lds_b[buf][(wc * 64 + nt * 16 + lrow) * 32 + quad * 8];
#pragma unroll
    for (int mt = 0; mt < 4; mt++)
#pragma unroll
      for (int nt = 0; nt < 4; nt++)
        acc[mt][nt] = __builtin_amdgcn_mfma_f32_16x16x32_fp8_fp8(af[mt], bfr[nt], acc[mt][nt], 0, 0, 0);
  };

  stage(0, 0);
  int curb = 0;
  int k0 = 0;
  for (; k0 + 32 < K; k0 += 32) {
    stage(curb ^ 1, k0 + 32);                         // prefetch next tile
    asm volatile("s_waitcnt vmcnt(2)" ::: "memory");  // wait ONLY current tile's loads
    __builtin_amdgcn_s_barrier();
    asm volatile("" ::: "memory");
    compute(curb);
    asm volatile("" ::: "memory");
    __builtin_amdgcn_s_barrier();
    curb ^= 1;
  }
  asm volatile("s_waitcnt vmcnt(0)" ::: "memory");
  __builtin_amdgcn_s_barrier();
  asm volatile("" ::: "memory");
  compute(curb);

#pragma unroll
  for (int mt = 0; mt < 4; mt++)
#pragma unroll
    for (int nt = 0; nt < 4; nt++)
#pragma unroll
      for (int r = 0; r < 4; r++) {
        int row = m0 + wr * 64 + mt * 16 + quad * 4 + r;
        int col = n0 + wc * 64 + nt * 16 + lrow;
        C8[(size_t)row * N + col] = f2fp8(acc[mt][nt][r]);
      }
}

// ---------- scan, stage 1: per-block sums over the 8 replicas ----------
__global__ __launch_bounds__(256) void gcn_scan_blocks_k(
    const int* __restrict__ cnt8, int* __restrict__ blockSum, int nNodes) {
  __shared__ int sw[4];
  int t = threadIdx.x;
  int i = blockIdx.x * 256 + t;
  int v = 0;
  if (i < nNodes) {
#pragma unroll
    for (int r = 0; r < NREP; r++) v += cnt8[r * NN + i];
  }
  for (int off = 32; off > 0; off >>= 1) v += __shfl_down(v, off);
  if ((t & 63) == 0) sw[t >> 6] = v;
  __syncthreads();
  if (t == 0) blockSum[blockIdx.x] = sw[0] + sw[1] + sw[2] + sw[3];
}

// ---------- scan, stage 2: block scan + redundant blockSum scan; emits rs, off8, dinv ----------
__global__ __launch_bounds__(256) void gcn_scan_final_k(
    const int* __restrict__ cnt8, const int* __restrict__ blockSum,
    int* __restrict__ rs, int* __restrict__ off8, float* __restrict__ dinv,
    int nNodes, int E) {
  __shared__ int sb[256];
  __shared__ int sc[256];
  int t = threadIdx.x;
  int i = blockIdx.x * 256 + t;
  int c[NREP];
  int v = 0;
  if (i < nNodes) {
#pragma unroll
    for (int r = 0; r < NREP; r++) { c[r] = cnt8[r * NN + i]; v += c[r]; }
  }
  sb[t] = v;
  int w = (t < SCAN_BLOCKS) ? blockSum[t] : 0;
  sc[t] = w;
  __syncthreads();
  for (int off = 1; off < 256; off <<= 1) {
    int x = (t >= off) ? sb[t - off] : 0;
    int y = (t >= off) ? sc[t - off] : 0;
    __syncthreads();
    sb[t] += x;
    sc[t] += y;
    __syncthreads();
  }
  int base = sc[blockIdx.x] - blockSum[blockIdx.x];  // exclusive prefix of blockSums
  if (i < nNodes) {
    int start = base + sb[t] - v;
    rs[i] = start;
    int o = start;
#pragma unroll
    for (int r = 0; r < NREP; r++) { off8[(size_t)i * NREP + r] = o; o += c[r]; }
    dinv[i] = rsqrtf(1.0f + (float)v);
  } else if (i < MPAD) {
    dinv[i] = 0.0f;   // pad rows
  }
  if (i == 0) rs[nNodes] = E;
}

// ---------- scatter: atomic-free; replica recomputed from edge index ----------
__global__ void gcn_scatter_k(const int* __restrict__ src, const int* __restrict__ dst,
                              const int* __restrict__ rank, const int* __restrict__ off8,
                              int* __restrict__ e4, int E) {
  int e = blockIdx.x * 256 + threadIdx.x;
  if (e < E) {
    int d = dst[e];
    int r = (e >> 8) & (NREP - 1);     // count block for e was e/256; replica = block&7
    e4[off8[(size_t)d * NREP + r] + rank[e]] = src[e];
  }
}

// ---------- fp8 GEMM, 2-phase double-buffered, epilogue scales rows by dinv (layer 2) ----------
template<int BN, int WTN>
__global__ __launch_bounds__(256) void gcn_gemm_f8_db_k(
    const unsigned char* __restrict__ A8,   // [MPAD x K] fp8
    const unsigned char* __restrict__ Bt8,  // [N x K]    fp8
    const float* __restrict__ dinv,         // [MPAD]
    unsigned char* __restrict__ C8,         // [MPAD x N] fp8 (pre-scaled by dinv[row])
    int K, int N) {
  static_assert(BN == 128, "db kernel assumes uniform 2 global_load_lds per thread");
  __shared__ __align__(16) unsigned char lds_a[2][128 * 32];
  __shared__ __align__(16) unsigned char lds_b[2][BN * 32];
  const int t = threadIdx.x;
  const int wave = t >> 6, lane = t & 63;
  const int wr = wave >> 1, wc = wave & 1;
  const int quad = lane >> 4, lrow = lane & 15;
  const int m0 = blockIdx.x * 128;
  const int n0 = blockIdx.y * BN;

  f32x4 acc[4][WTN] = {};

  auto stage = [&](int buf, int k0) {
    int r = t >> 1, c = (t & 1) * 16;
    async_copy16(&A8[(size_t)(m0 + r) * K + k0 + c], &lds_a[buf][t * 16]);
    async_copy16(&Bt8[(size_t)(n0 + r) * K + k0 + c], &lds_b[buf][t * 16]);
  };
  auto compute = [&](int buf) {
    long af[4], bfr[WTN];
#pragma unroll
    for (int mt = 0; mt < 4; mt++)
      af[mt] = *(const long*)&lds_a[buf][(wr * 64 + mt * 16 + lrow) * 32 + quad * 8];
#pragma unroll
    for (int nt = 0; nt < WTN; nt++)
      bfr[nt] = *(const long*)&lds_b[buf][(wc * (BN / 2) + nt * 16 + lrow) * 32 + quad * 8];
#pragma unroll
    for (int mt = 0; mt < 4; mt++)
#pragma unroll
      for (int nt = 0; nt < WTN; nt++)
        acc[mt][nt] = __builtin_amdgcn_mfma_f32_16x16x32_fp8_fp8(af[mt], bfr[nt], acc[mt][nt], 0, 0, 0);
  };

  stage(0, 0);
  int curb = 0;
  int k0 = 0;
  for (; k0 + 32 < K; k0 += 32) {
    stage(curb ^ 1, k0 + 32);                         // prefetch next tile
    asm volatile("s_waitcnt vmcnt(2)" ::: "memory");  // wait ONLY current tile's loads
    __builtin_amdgcn_s_barrier();
    asm volatile("" ::: "memory");
    compute(curb);
    asm volatile("" ::: "memory");
    __builtin_amdgcn_s_barrier();
    curb ^= 1;
  }
  asm volatile("s_waitcnt vmcnt(0)" ::: "memory");
  __builtin_amdgcn_s_barrier();
  asm volatile("" ::: "memory");
  compute(curb);

#pragma unroll
  for (int mt = 0; mt < 4; mt++)
#pragma unroll
    for (int r = 0; r < 4; r++) {
      int row = m0 + wr * 64 + mt * 16 + quad * 4 + r;
      float dv = dinv[row];
#pragma unroll
      for (int nt = 0; nt < WTN; nt++) {
        int col = n0 + wc * (BN / 2) + nt * 16 + lrow;
        C8[(size_t)row * N + col] = f2fp8(acc[mt][nt][r] * dv);
      }
    }
}

// ---------- fp8 GEMM, single-buffered (layer 3: BN=64), dinv epilogue ----------
template<int BN, int WTN>
__global__ __launch_bounds__(256) void gcn_gemm_f8_s_k(
    const unsigned char* __restrict__ A8, const unsigned char* __restrict__ Bt8,
    const float* __restrict__ dinv, unsigned char* __restrict__ C8, int K, int N) {
  __shared__ __align__(16) unsigned char lds_a[128 * 32];
  __shared__ __align__(16) unsigned char lds_b[BN * 32];
  const int t = threadIdx.x;
  const int wave = t >> 6, lane = t & 63;
  const int wr = wave >> 1, wc = wave & 1;
  const int quad = lane >> 4, lrow = lane & 15;
  const int m0 = blockIdx.x * 128;
  const int n0 = blockIdx.y * BN;

  f32x4 acc[4][WTN] = {};

  for (int k0 = 0; k0 < K; k0 += 32) {
    __syncthreads();
    {
      int r = t >> 1, c = (t & 1) * 16;
      async_copy16(&A8[(size_t)(m0 + r) * K + k0 + c], &lds_a[t * 16]);
    }
    for (int q = t; q < BN * 2; q += 256) {
      int r = q >> 1, c = (q & 1) * 16;
      async_copy16(&Bt8[(size_t)(n0 + r) * K + k0 + c], &lds_b[q * 16]);
    }
    __syncthreads();
    long af[4], bfr[WTN];
#pragma unroll
    for (int mt = 0; mt < 4; mt++)
      af[mt] = *(const long*)&lds_a[(wr * 64 + mt * 16 + lrow) * 32 + quad * 8];
#pragma unroll
    for (int nt = 0; nt < WTN; nt++)
      bfr[nt] = *(const long*)&lds_b[(wc * (BN / 2) + nt * 16 + lrow) * 32 + quad * 8];
#pragma unroll
    for (int mt = 0; mt < 4; mt++)
#pragma unroll
      for (int nt = 0; nt < WTN; nt++)
        acc[mt][nt] = __builtin_amdgcn_mfma_f32_16x16x32_fp8_fp8(af[mt], bfr[nt], acc[mt][nt], 0, 0, 0);
  }

#pragma unroll
  for (int mt = 0; mt < 4; mt++)
#pragma unroll
    for (int r = 0; r < 4; r++) {
      int row = m0 + wr * 64 + mt * 16 + quad * 4 + r;
      float dv = dinv[row];
#pragma unroll
      for (int nt = 0; nt < WTN; nt++) {
        int col = n0 + wc * (BN / 2) + nt * 16 + lrow;
        C8[(size_t)row * N + col] = f2fp8(acc[mt][nt][r] * dv);
      }
    }
}

// ---------- aggregation (D=256), 4 gathers in flight per 16-lane group (proven depth) ----------
// WSRC=1 (layer 1): h8 unscaled -> per-edge weight dinv[src], self weight dinv[i].
// WSRC=0 (layer 2): rows are g = dinv*h -> weight 1, self weight 1.
// Both finish with out = relu(dinv_i * sum + bias).
template<int D, int WSRC>
__global__ __launch_bounds__(256) void gcn_agg_relu_k(
    const unsigned char* __restrict__ g8, const int* __restrict__ rs,
    const int* __restrict__ e4, const float* __restrict__ dinv,
    const float* __restrict__ bias, unsigned char* __restrict__ out8, int nNodes) {
  int wave = threadIdx.x >> 6, lane = threadIdx.x & 63;
  int i = blockIdx.x * 4 + wave;
  if (i >= nNodes) return;
  int q = lane >> 4, sub = lane & 15;
  int f0 = sub * 16;                       // 16 features per lane
  float di = dinv[i];
  uint4 dself = *(const uint4*)&g8[(size_t)i * D + f0];
  float sv[16];
  fp8x16_to_f32(dself, sv);
  float wself = (q == 0) ? (WSRC ? di : 1.0f) : 0.0f;
  float acc[16];
#pragma unroll
  for (int j = 0; j < 16; j++) acc[j] = sv[j] * wself;

  int e0 = rs[i], e1 = rs[i + 1];
  int nIter = (e1 - e0 + 15) >> 4;         // 16 edges per iteration (4 per group)
  int e = e0 + q;
  for (int k = 0; k < nIter; k++) {
    int idx[4]; float w[4];
#pragma unroll
    for (int u = 0; u < 4; u++) {
      int ee = e + 4 * u;
      bool v = ee < e1;
      idx[u] = v ? e4[ee] : 0;
      w[u] = v ? (WSRC ? dinv[idx[u]] : 1.0f) : 0.0f;
    }
    uint4 d0 = *(const uint4*)&g8[(size_t)idx[0] * D + f0];
    uint4 d1 = *(const uint4*)&g8[(size_t)idx[1] * D + f0];
    uint4 d2 = *(const uint4*)&g8[(size_t)idx[2] * D + f0];
    uint4 d3 = *(const uint4*)&g8[(size_t)idx[3] * D + f0];
    float r[16];
    fp8x16_to_f32(d0, r);
#pragma unroll
    for (int j = 0; j < 16; j++) acc[j] += r[j] * w[0];
    fp8x16_to_f32(d1, r);
#pragma unroll
    for (int j = 0; j < 16; j++) acc[j] += r[j] * w[1];
    fp8x16_to_f32(d2, r);
#pragma unroll
    for (int j = 0; j < 16; j++) acc[j] += r[j] * w[2];
    fp8x16_to_f32(d3, r);
#pragma unroll
    for (int j = 0; j < 16; j++) acc[j] += r[j] * w[3];
    e += 16;
  }
#pragma unroll
  for (int j = 0; j < 16; j++) {
    acc[j] += __shfl_xor(acc[j], 16);
    acc[j] += __shfl_xor(acc[j], 32);
  }
  if (q == 0) {
    float4 bb0 = *(const float4*)&bias[f0];
    float4 bb1 = *(const float4*)&bias[f0 + 4];
    float4 bb2 = *(const float4*)&bias[f0 + 8];
    float4 bb3 = *(const float4*)&bias[f0 + 12];
    float bv[16] = {bb0.x, bb0.y, bb0.z, bb0.w, bb1.x, bb1.y, bb1.z, bb1.w,
                    bb2.x, bb2.y, bb2.z, bb2.w, bb3.x, bb3.y, bb3.z, bb3.w};
    float r[16];
#pragma unroll
    for (int j = 0; j < 16; j++) {
      float z = di * acc[j] + bv[j];
      r[j] = z > 0.0f ? z : 0.0f;
    }
    uint4 o;
    o.x = f2fp8x4(r[0], r[1], r[2], r[3]);
    o.y = f2fp8x4(r[4], r[5], r[6], r[7]);
    o.z = f2fp8x4(r[8], r[9], r[10], r[11]);
    o.w = f2fp8x4(r[12], r[13], r[14], r[15]);
    *(uint4*)&out8[(size_t)i * D + f0] = o;
  }
}

// final layer: D=64 g-rows; 2 gathers in flight per 16-lane group (proven depth)
__global__ __launch_bounds__(256) void gcn_agg_final_k(
    const unsigned char* __restrict__ g8, const int* __restrict__ rs,
    const int* __restrict__ e4, const float* __restrict__ dinv,
    const float* __restrict__ bias, float* __restrict__ out, int nNodes) {
  int wave = threadIdx.x >> 6, lane = threadIdx.x & 63;
  int i = blockIdx.x * 4 + wave;
  if (i >= nNodes) return;
  int qtr = lane >> 4, sub = lane & 15;
  int f0 = sub * 4;
  float di = dinv[i];
  unsigned int dself = *(const unsigned int*)&g8[(size_t)i * 64 + f0];
  float sv[4];
  fp8x4_to_f32(dself, sv);
  float wself = (qtr == 0) ? 1.0f : 0.0f;
  float acc[4];
#pragma unroll
  for (int j = 0; j < 4; j++) acc[j] = sv[j] * wself;

  int e0 = rs[i], e1 = rs[i + 1];
  int nIter = (e1 - e0 + 7) >> 3;
  int e = e0 + qtr;
  for (int k = 0; k < nIter; k++) {
    int idx[2]; float w[2];
#pragma unroll
    for (int u = 0; u < 2; u++) {
      int ee = e + 4 * u;
      bool v = ee < e1;
      idx[u] = v ? e4[ee] : 0;
      w[u] = v ? 1.0f : 0.0f;
    }
    unsigned int d0 = *(const unsigned int*)&g8[(size_t)idx[0] * 64 + f0];
    unsigned int d1 = *(const unsigned int*)&g8[(size_t)idx[1] * 64 + f0];
    float r0[4], r1[4];
    fp8x4_to_f32(d0, r0); fp8x4_to_f32(d1, r1);
#pragma unroll
    for (int j = 0; j < 4; j++)
      acc[j] += r0[j] * w[0] + r1[j] * w[1];
    e += 8;
  }
#pragma unroll
  for (int j = 0; j < 4; j++) {
    acc[j] += __shfl_xor(acc[j], 16);
    acc[j] += __shfl_xor(acc[j], 32);
    acc[j] = di * acc[j] + bias[f0 + j];
  }
  // softmax over 64 features (16 lanes x 4 regs; all lanes hold full sums)
  float m = fmaxf(fmaxf(acc[0], acc[1]), fmaxf(acc[2], acc[3]));
#pragma unroll
  for (int off = 8; off > 0; off >>= 1) m = fmaxf(m, __shfl_xor(m, off));
  float ex[4], s = 0.0f;
#pragma unroll
  for (int j = 0; j < 4; j++) { ex[j] = __expf(acc[j] - m); s += ex[j]; }
#pragma unroll
  for (int off = 8; off > 0; off >>= 1) s += __shfl_xor(s, off);
  float rcs = 1.0f / s;
  float p[4], s2 = 0.0f;
#pragma unroll
  for (int j = 0; j < 4; j++) { p[j] = ex[j] * rcs; s2 += __expf(p[j]); }
#pragma unroll
  for (int off = 8; off > 0; off >>= 1) s2 += __shfl_xor(s2, off);
  float ls = __logf(s2);
  if (qtr == 0) {
    float4 o; o.x = p[0] - ls; o.y = p[1] - ls; o.z = p[2] - ls; o.w = p[3] - ls;
    *(float4*)&out[(size_t)i * 64 + f0] = o;
  }
}

// ---------- launch ----------
extern "C" void kernel_launch(void* const* d_in, const int* in_sizes, int n_in,
                              void* d_out, int out_size, void* d_ws, size_t ws_size,
                              hipStream_t stream) {
  const float* x    = (const float*)d_in[0];
  const int*   eidx = (const int*)d_in[1];
  const float* W1   = (const float*)d_in[2];
  const float* b1   = (const float*)d_in[3];
  const float* W2   = (const float*)d_in[4];
  const float* b2   = (const float*)d_in[5];
  const float* W3   = (const float*)d_in[6];
  const float* b3   = (const float*)d_in[7];
  float* out = (float*)d_out;

  const int E = in_sizes[1] / 2;            // 800000
  const int* src = eidx;
  const int* dst = eidx + E;

  char* p = (char*)d_ws;
  auto alloc = [&](size_t bytes) -> void* {
    void* r = (void*)p;
    p += (bytes + 255) & ~(size_t)255;
    return r;
  };
  unsigned char*  x8   = (unsigned char*)alloc((size_t)MPAD * 512);
  unsigned char*  g8   = (unsigned char*)alloc((size_t)MPAD * 256);  // gemm out fp8
  unsigned char*  a8   = (unsigned char*)alloc((size_t)MPAD * 256);  // agg out fp8
  unsigned char*  g83  = (unsigned char*)alloc((size_t)MPAD * 64);
  unsigned char*  W1T8 = (unsigned char*)alloc((size_t)256 * 512);
  unsigned char*  W2T8 = (unsigned char*)alloc((size_t)256 * 256);
  unsigned char*  W3T8 = (unsigned char*)alloc((size_t)64 * 256);
  int*   cnt8 = (int*)alloc((size_t)NREP * NN * 4);   // 8 XCD-local replicas
  int*   rs   = (int*)alloc((size_t)(NN + 1) * 4);
  int*   off8 = (int*)alloc((size_t)NN * NREP * 4);   // per-(node,replica) scatter base
  int*   rank = (int*)alloc((size_t)E * 4);
  float* dinv = (float*)alloc((size_t)MPAD * 4);
  int*   e4   = (int*)alloc((size_t)(E + 64) * 4);
  int*   bsum = (int*)alloc((size_t)SCAN_BLOCKS * 4);

  const int EB = (E + 255) / 256;  // 3125
  // 1. prep (pure streaming; zeroes cnt8 replicas)
  gcn_prep_k<<<XB_BLOCKS + WB_BLOCKS, 256, 0, stream>>>(
      x, x8, W1, W2, W3, W1T8, W2T8, W3T8, cnt8);
  // 2. XCD-local count + layer-1 GEMM, one heterogeneous dispatch
  gcn_count_gemm1_k<<<COUNT_BLOCKS + GEMM1_BLOCKS, 256, 0, stream>>>(
      x8, W1T8, g8, dst, cnt8, rank, E);
  // 3-4. scan (2 kernels, R6-proven shape), emits rs + off8 + dinv
  gcn_scan_blocks_k<<<SCAN_BLOCKS, 256, 0, stream>>>(cnt8, bsum, NN);
  gcn_scan_final_k<<<SCAN_BLOCKS, 256, 0, stream>>>(cnt8, bsum, rs, off8, dinv, NN, E);
  // 5. scatter (replica recomputed from edge index)
  gcn_scatter_k<<<EB, 256, 0, stream>>>(src, dst, rank, off8, e4, E);
  // 6. layer 1 aggregation (h unscaled -> per-edge dinv[src] weights)
  gcn_agg_relu_k<256, 1><<<(NN + 3) / 4, 256, 0, stream>>>(g8, rs, e4, dinv, b1, a8, NN);
  const int MB = MPAD / 128;  // 391
  // 7-8. layer 2
  gcn_gemm_f8_db_k<128, 4><<<dim3(MB, 2), 256, 0, stream>>>(a8, W2T8, dinv, g8, 256, 256);
  gcn_agg_relu_k<256, 0><<<(NN + 3) / 4, 256, 0, stream>>>(g8, rs, e4, dinv, b2, a8, NN);
  // 9-10. layer 3 + fused softmax/log_softmax
  gcn_gemm_f8_s_k<64, 2><<<dim3(MB, 1), 256, 0, stream>>>(a8, W3T8, dinv, g83, 256, 64);
  gcn_agg_final_k<<<(NN + 3) / 4, 256, 0, stream>>>(g83, rs, e4, dinv, b3, out, NN);

  (void)n_in; (void)out_size; (void)ws_size;
}

// Round 12
// 384.047 us; speedup vs baseline: 1.0561x; 1.0281x over previous
//
#include <hip/hip_runtime.h>
#include <cstdint>
#include <cstddef>

// ---------- types / helpers ----------
typedef float  f32x4  __attribute__((ext_vector_type(4)));
typedef float  f32x2  __attribute__((ext_vector_type(2)));

__device__ __forceinline__ unsigned int f2fp8x4(float a, float b, float c, float d) {
  int v = __builtin_amdgcn_cvt_pk_fp8_f32(a, b, 0, false);
  v = __builtin_amdgcn_cvt_pk_fp8_f32(c, d, v, true);
  return (unsigned int)v;
}
__device__ __forceinline__ unsigned char f2fp8(float f) {
  return (unsigned char)(__builtin_amdgcn_cvt_pk_fp8_f32(f, f, 0, false) & 0xff);
}
__device__ __forceinline__ void fp8x8_to_f32(uint2 d, float* f) {
  f32x2 a = __builtin_amdgcn_cvt_pk_f32_fp8((int)d.x, false);
  f32x2 b = __builtin_amdgcn_cvt_pk_f32_fp8((int)d.x, true);
  f32x2 c = __builtin_amdgcn_cvt_pk_f32_fp8((int)d.y, false);
  f32x2 e = __builtin_amdgcn_cvt_pk_f32_fp8((int)d.y, true);
  f[0] = a.x; f[1] = a.y; f[2] = b.x; f[3] = b.y;
  f[4] = c.x; f[5] = c.y; f[6] = e.x; f[7] = e.y;
}
__device__ __forceinline__ void fp8x4_to_f32(unsigned int d, float* f) {
  f32x2 a = __builtin_amdgcn_cvt_pk_f32_fp8((int)d, false);
  f32x2 b = __builtin_amdgcn_cvt_pk_f32_fp8((int)d, true);
  f[0] = a.x; f[1] = a.y; f[2] = b.x; f[3] = b.y;
}
__device__ __forceinline__ void fp8x16_to_f32(uint4 d, float* f) {
  uint2 lo; lo.x = d.x; lo.y = d.y;
  uint2 hi; hi.x = d.z; hi.y = d.w;
  fp8x8_to_f32(lo, f);
  fp8x8_to_f32(hi, f + 8);
}

// async global->LDS, 16B per lane. LDS dest must be lane-contiguous in wave order.
__device__ __forceinline__ void async_copy16(const void* g, void* l) {
  __builtin_amdgcn_global_load_lds(
      (const __attribute__((address_space(1))) unsigned int*)g,
      (__attribute__((address_space(3))) unsigned int*)l, 16, 0, 0);
}

#define NN 50000
#define MPAD 50048       // 391 * 128
#define SCAN_BLOCKS 196  // ceil(50000/256); 196*256=50176 >= MPAD

// prep block ranges: X (6256) + W1 (32) + W2 (16) + W3 (4)
#define XB_BLOCKS 6256   // MPAD*512/16/256
#define WB_BLOCKS 52

// ---------- zero cnt (must precede prep's fused count atomics) ----------
__global__ __launch_bounds__(256) void gcn_zero_k(int* __restrict__ cnt) {
  int i = blockIdx.x * 256 + threadIdx.x;
  if (i < NN) cnt[i] = 0;
}

// ---------- prep: X,W -> fp8 (transposed W), FUSED degree-count with rank capture ----------
// Issue order: dst load + X loads FIRST, then the atomic, x8 store, and only at
// the END the rank store (the only consumer of the atomic's return value).
__global__ __launch_bounds__(256) void gcn_prep_k(
    const float* __restrict__ X, unsigned char* __restrict__ x8,
    const float* __restrict__ W1, const float* __restrict__ W2,
    const float* __restrict__ W3,
    unsigned char* __restrict__ W1T8, unsigned char* __restrict__ W2T8,
    unsigned char* __restrict__ W3T8,
    const int* __restrict__ dst, int* __restrict__ cnt, int* __restrict__ rank, int E) {
  int b = blockIdx.x;
  if (b < XB_BLOCKS) {
    int e = b * 256 + threadIdx.x;
    bool hasE = (e < E);
    int d = hasE ? dst[e] : 0;            // coalesced, issued first
    // X [NN x 512] f32 -> x8 [MPAD x 512] fp8, 16 elems/thread
    int idx16 = e * 16;
    int row = idx16 >> 9;
    float4 v0, v1, v2, v3;
    bool live = (row < NN);
    if (live) {
      const float* s = &X[idx16];
      v0 = *(const float4*)s;             // streaming loads in flight
      v1 = *(const float4*)(s + 4);
      v2 = *(const float4*)(s + 8);
      v3 = *(const float4*)(s + 12);
    }
    int rnk = 0;
    if (hasE) rnk = atomicAdd(&cnt[d], 1);  // issued after X loads
    uint4 o;
    if (live) {
      o.x = f2fp8x4(v0.x, v0.y, v0.z, v0.w);
      o.y = f2fp8x4(v1.x, v1.y, v1.z, v1.w);
      o.z = f2fp8x4(v2.x, v2.y, v2.z, v2.w);
      o.w = f2fp8x4(v3.x, v3.y, v3.z, v3.w);
    } else {
      o = uint4{0, 0, 0, 0};
    }
    *(uint4*)&x8[idx16] = o;
    if (hasE) rank[e] = rnk;              // the only consumer of the atomic return
  } else {
    int wb = b - XB_BLOCKS;
    if (wb < 32) {
      // W1 [512x256] -> W1T8 [256x512] fp8, 16/thread
      int idx16 = (wb * 256 + threadIdx.x) * 16;
      int n = idx16 >> 9;
      float f[16];
#pragma unroll
      for (int j = 0; j < 16; j++) f[j] = W1[(size_t)((idx16 & 511) + j) * 256 + n];
      uint4 o;
      o.x = f2fp8x4(f[0], f[1], f[2], f[3]);
      o.y = f2fp8x4(f[4], f[5], f[6], f[7]);
      o.z = f2fp8x4(f[8], f[9], f[10], f[11]);
      o.w = f2fp8x4(f[12], f[13], f[14], f[15]);
      *(uint4*)&W1T8[idx16] = o;
    } else if (wb < 48) {
      // W2 [256x256] -> W2T8 [256x256] fp8
      int idx16 = ((wb - 32) * 256 + threadIdx.x) * 16;
      int n = idx16 >> 8;
      float f[16];
#pragma unroll
      for (int j = 0; j < 16; j++) f[j] = W2[(size_t)((idx16 & 255) + j) * 256 + n];
      uint4 o;
      o.x = f2fp8x4(f[0], f[1], f[2], f[3]);
      o.y = f2fp8x4(f[4], f[5], f[6], f[7]);
      o.z = f2fp8x4(f[8], f[9], f[10], f[11]);
      o.w = f2fp8x4(f[12], f[13], f[14], f[15]);
      *(uint4*)&W2T8[idx16] = o;
    } else {
      // W3 [256x64] -> W3T8 [64x256] fp8
      int idx16 = ((wb - 48) * 256 + threadIdx.x) * 16;
      int n = idx16 >> 8;
      float f[16];
#pragma unroll
      for (int j = 0; j < 16; j++) f[j] = W3[(size_t)((idx16 & 255) + j) * 64 + n];
      uint4 o;
      o.x = f2fp8x4(f[0], f[1], f[2], f[3]);
      o.y = f2fp8x4(f[4], f[5], f[6], f[7]);
      o.z = f2fp8x4(f[8], f[9], f[10], f[11]);
      o.w = f2fp8x4(f[12], f[13], f[14], f[15]);
      *(uint4*)&W3T8[idx16] = o;
    }
  }
}

// ---------- scan, stage 1: per-block sums ----------
__global__ __launch_bounds__(256) void gcn_scan_blocks_k(
    const int* __restrict__ cnt, int* __restrict__ blockSum, int nNodes) {
  __shared__ int sw[4];
  int t = threadIdx.x;
  int i = blockIdx.x * 256 + t;
  int v = (i < nNodes) ? cnt[i] : 0;
  for (int off = 32; off > 0; off >>= 1) v += __shfl_down(v, off);
  if ((t & 63) == 0) sw[t >> 6] = v;
  __syncthreads();
  if (t == 0) blockSum[blockIdx.x] = sw[0] + sw[1] + sw[2] + sw[3];
}

// ---------- scan, stage 2: block scan + redundant in-block scan of blockSums ----------
__global__ __launch_bounds__(256) void gcn_scan_final_k(
    const int* __restrict__ cnt, const int* __restrict__ blockSum,
    int* __restrict__ rs, float* __restrict__ dinv, int nNodes, int E) {
  __shared__ int sb[256];
  __shared__ int sc[256];
  int t = threadIdx.x;
  int i = blockIdx.x * 256 + t;
  int v = (i < nNodes) ? cnt[i] : 0;
  sb[t] = v;
  // redundant scan of the 196 block sums (each block does its own copy)
  int w = (t < SCAN_BLOCKS) ? blockSum[t] : 0;
  sc[t] = w;
  __syncthreads();
  for (int off = 1; off < 256; off <<= 1) {
    int x = (t >= off) ? sb[t - off] : 0;
    int y = (t >= off) ? sc[t - off] : 0;
    __syncthreads();
    sb[t] += x;
    sc[t] += y;
    __syncthreads();
  }
  int base = sc[blockIdx.x] - blockSum[blockIdx.x];  // exclusive prefix of blockSums
  if (i < nNodes) {
    rs[i] = base + sb[t] - v;
    dinv[i] = rsqrtf(1.0f + (float)v);
  } else if (i < MPAD) {
    dinv[i] = 0.0f;   // pad rows: GEMM epilogue scales poison to 0
  }
  if (i == 0) rs[nNodes] = E;
}

// ---------- scatter: atomic-free (rank precomputed), src-only payload ----------
__global__ void gcn_scatter_k(const int* __restrict__ src, const int* __restrict__ dst,
                              const int* __restrict__ rank, const int* __restrict__ rs,
                              int* __restrict__ e4, int E) {
  int e = blockIdx.x * 256 + threadIdx.x;
  if (e < E) {
    int d = dst[e];
    e4[rs[d] + rank[e]] = src[e];
  }
}

// ---------- fp8 GEMM, 2-phase double-buffered, epilogue scales rows by dinv ----------
template<int BN, int WTN>
__global__ __launch_bounds__(256) void gcn_gemm_f8_db_k(
    const unsigned char* __restrict__ A8,   // [MPAD x K] fp8
    const unsigned char* __restrict__ Bt8,  // [N x K]    fp8
    const float* __restrict__ dinv,         // [MPAD]
    unsigned char* __restrict__ C8,         // [MPAD x N] fp8 (pre-scaled by dinv[row])
    int K, int N) {
  static_assert(BN == 128, "db kernel assumes uniform 2 global_load_lds per thread");
  __shared__ __align__(16) unsigned char lds_a[2][128 * 32];
  __shared__ __align__(16) unsigned char lds_b[2][BN * 32];
  const int t = threadIdx.x;
  const int wave = t >> 6, lane = t & 63;
  const int wr = wave >> 1, wc = wave & 1;
  const int quad = lane >> 4, lrow = lane & 15;
  const int m0 = blockIdx.x * 128;
  const int n0 = blockIdx.y * BN;

  f32x4 acc[4][WTN] = {};

  auto stage = [&](int buf, int k0) {
    int r = t >> 1, c = (t & 1) * 16;
    async_copy16(&A8[(size_t)(m0 + r) * K + k0 + c], &lds_a[buf][t * 16]);
    async_copy16(&Bt8[(size_t)(n0 + r) * K + k0 + c], &lds_b[buf][t * 16]);
  };
  auto compute = [&](int buf) {
    long af[4], bfr[WTN];
#pragma unroll
    for (int mt = 0; mt < 4; mt++)
      af[mt] = *(const long*)&lds_a[buf][(wr * 64 + mt * 16 + lrow) * 32 + quad * 8];
#pragma unroll
    for (int nt = 0; nt < WTN; nt++)
      bfr[nt] = *(const long*)&lds_b[buf][(wc * (BN / 2) + nt * 16 + lrow) * 32 + quad * 8];
#pragma unroll
    for (int mt = 0; mt < 4; mt++)
#pragma unroll
      for (int nt = 0; nt < WTN; nt++)
        acc[mt][nt] = __builtin_amdgcn_mfma_f32_16x16x32_fp8_fp8(af[mt], bfr[nt], acc[mt][nt], 0, 0, 0);
  };

  stage(0, 0);
  int curb = 0;
  int k0 = 0;
  for (; k0 + 32 < K; k0 += 32) {
    stage(curb ^ 1, k0 + 32);                         // prefetch next tile
    asm volatile("s_waitcnt vmcnt(2)" ::: "memory");  // wait ONLY current tile's loads
    __builtin_amdgcn_s_barrier();
    asm volatile("" ::: "memory");
    compute(curb);
    asm volatile("" ::: "memory");
    __builtin_amdgcn_s_barrier();
    curb ^= 1;
  }
  asm volatile("s_waitcnt vmcnt(0)" ::: "memory");
  __builtin_amdgcn_s_barrier();
  asm volatile("" ::: "memory");
  compute(curb);

#pragma unroll
  for (int mt = 0; mt < 4; mt++)
#pragma unroll
    for (int r = 0; r < 4; r++) {
      int row = m0 + wr * 64 + mt * 16 + quad * 4 + r;
      float dv = dinv[row];
#pragma unroll
      for (int nt = 0; nt < WTN; nt++) {
        int col = n0 + wc * (BN / 2) + nt * 16 + lrow;
        C8[(size_t)row * N + col] = f2fp8(acc[mt][nt][r] * dv);
      }
    }
}

// ---------- fp8 GEMM, single-buffered (layer 3: BN=64), dinv epilogue ----------
template<int BN, int WTN>
__global__ __launch_bounds__(256) void gcn_gemm_f8_s_k(
    const unsigned char* __restrict__ A8, const unsigned char* __restrict__ Bt8,
    const float* __restrict__ dinv, unsigned char* __restrict__ C8, int K, int N) {
  __shared__ __align__(16) unsigned char lds_a[128 * 32];
  __shared__ __align__(16) unsigned char lds_b[BN * 32];
  const int t = threadIdx.x;
  const int wave = t >> 6, lane = t & 63;
  const int wr = wave >> 1, wc = wave & 1;
  const int quad = lane >> 4, lrow = lane & 15;
  const int m0 = blockIdx.x * 128;
  const int n0 = blockIdx.y * BN;

  f32x4 acc[4][WTN] = {};

  for (int k0 = 0; k0 < K; k0 += 32) {
    __syncthreads();
    {
      int r = t >> 1, c = (t & 1) * 16;
      async_copy16(&A8[(size_t)(m0 + r) * K + k0 + c], &lds_a[t * 16]);
    }
    for (int q = t; q < BN * 2; q += 256) {
      int r = q >> 1, c = (q & 1) * 16;
      async_copy16(&Bt8[(size_t)(n0 + r) * K + k0 + c], &lds_b[q * 16]);
    }
    __syncthreads();
    long af[4], bfr[WTN];
#pragma unroll
    for (int mt = 0; mt < 4; mt++)
      af[mt] = *(const long*)&lds_a[(wr * 64 + mt * 16 + lrow) * 32 + quad * 8];
#pragma unroll
    for (int nt = 0; nt < WTN; nt++)
      bfr[nt] = *(const long*)&lds_b[(wc * (BN / 2) + nt * 16 + lrow) * 32 + quad * 8];
#pragma unroll
    for (int mt = 0; mt < 4; mt++)
#pragma unroll
      for (int nt = 0; nt < WTN; nt++)
        acc[mt][nt] = __builtin_amdgcn_mfma_f32_16x16x32_fp8_fp8(af[mt], bfr[nt], acc[mt][nt], 0, 0, 0);
  }

#pragma unroll
  for (int mt = 0; mt < 4; mt++)
#pragma unroll
    for (int r = 0; r < 4; r++) {
      int row = m0 + wr * 64 + mt * 16 + quad * 4 + r;
      float dv = dinv[row];
#pragma unroll
      for (int nt = 0; nt < WTN; nt++) {
        int col = n0 + wc * (BN / 2) + nt * 16 + lrow;
        C8[(size_t)row * N + col] = f2fp8(acc[mt][nt][r] * dv);
      }
    }
}

// ---------- aggregation (D=256): rows are g = dinv*h; out = relu(dinv_i*(sum+self)+b) ----------
template<int D>
__global__ __launch_bounds__(256) void gcn_agg_relu_k(
    const unsigned char* __restrict__ g8, const int* __restrict__ rs,
    const int* __restrict__ e4, const float* __restrict__ dinv,
    const float* __restrict__ bias, unsigned char* __restrict__ out8, int nNodes) {
  int wave = threadIdx.x >> 6, lane = threadIdx.x & 63;
  int i = blockIdx.x * 4 + wave;
  if (i >= nNodes) return;
  int q = lane >> 4, sub = lane & 15;
  int f0 = sub * 16;                       // 16 features per lane
  float di = dinv[i];
  uint4 dself = *(const uint4*)&g8[(size_t)i * D + f0];
  float sv[16];
  fp8x16_to_f32(dself, sv);
  float wself = (q == 0) ? 1.0f : 0.0f;    // self term: g[i] (dinv folded into g)
  float acc[16];
#pragma unroll
  for (int j = 0; j < 16; j++) acc[j] = sv[j] * wself;

  int e0 = rs[i], e1 = rs[i + 1];
  int nIter = (e1 - e0 + 15) >> 4;         // 16 edges per iteration
  int e = e0 + q;
  for (int k = 0; k < nIter; k++) {
    int idx[4]; float w[4];
#pragma unroll
    for (int u = 0; u < 4; u++) {
      int ee = e + 4 * u;
      bool v = ee < e1;
      idx[u] = v ? e4[ee] : 0;
      w[u] = v ? 1.0f : 0.0f;
    }
    uint4 d0 = *(const uint4*)&g8[(size_t)idx[0] * D + f0];
    uint4 d1 = *(const uint4*)&g8[(size_t)idx[1] * D + f0];
    uint4 d2 = *(const uint4*)&g8[(size_t)idx[2] * D + f0];
    uint4 d3 = *(const uint4*)&g8[(size_t)idx[3] * D + f0];
    float r[16];
    fp8x16_to_f32(d0, r);
#pragma unroll
    for (int j = 0; j < 16; j++) acc[j] += r[j] * w[0];
    fp8x16_to_f32(d1, r);
#pragma unroll
    for (int j = 0; j < 16; j++) acc[j] += r[j] * w[1];
    fp8x16_to_f32(d2, r);
#pragma unroll
    for (int j = 0; j < 16; j++) acc[j] += r[j] * w[2];
    fp8x16_to_f32(d3, r);
#pragma unroll
    for (int j = 0; j < 16; j++) acc[j] += r[j] * w[3];
    e += 16;
  }
#pragma unroll
  for (int j = 0; j < 16; j++) {
    acc[j] += __shfl_xor(acc[j], 16);
    acc[j] += __shfl_xor(acc[j], 32);
  }
  if (q == 0) {
    float4 bb0 = *(const float4*)&bias[f0];
    float4 bb1 = *(const float4*)&bias[f0 + 4];
    float4 bb2 = *(const float4*)&bias[f0 + 8];
    float4 bb3 = *(const float4*)&bias[f0 + 12];
    float bv[16] = {bb0.x, bb0.y, bb0.z, bb0.w, bb1.x, bb1.y, bb1.z, bb1.w,
                    bb2.x, bb2.y, bb2.z, bb2.w, bb3.x, bb3.y, bb3.z, bb3.w};
    float r[16];
#pragma unroll
    for (int j = 0; j < 16; j++) {
      float z = di * acc[j] + bv[j];
      r[j] = z > 0.0f ? z : 0.0f;
    }
    uint4 o;
    o.x = f2fp8x4(r[0], r[1], r[2], r[3]);
    o.y = f2fp8x4(r[4], r[5], r[6], r[7]);
    o.z = f2fp8x4(r[8], r[9], r[10], r[11]);
    o.w = f2fp8x4(r[12], r[13], r[14], r[15]);
    *(uint4*)&out8[(size_t)i * D + f0] = o;
  }
}

// final layer: D=64 g-rows; sum + self, scale by dinv_i, bias, softmax+log_softmax
__global__ __launch_bounds__(256) void gcn_agg_final_k(
    const unsigned char* __restrict__ g8, const int* __restrict__ rs,
    const int* __restrict__ e4, const float* __restrict__ dinv,
    const float* __restrict__ bias, float* __restrict__ out, int nNodes) {
  int wave = threadIdx.x >> 6, lane = threadIdx.x & 63;
  int i = blockIdx.x * 4 + wave;
  if (i >= nNodes) return;
  int qtr = lane >> 4, sub = lane & 15;
  int f0 = sub * 4;
  float di = dinv[i];
  unsigned int dself = *(const unsigned int*)&g8[(size_t)i * 64 + f0];
  float sv[4];
  fp8x4_to_f32(dself, sv);
  float wself = (qtr == 0) ? 1.0f : 0.0f;
  float acc[4];
#pragma unroll
  for (int j = 0; j < 4; j++) acc[j] = sv[j] * wself;

  int e0 = rs[i], e1 = rs[i + 1];
  int nIter = (e1 - e0 + 7) >> 3;
  int e = e0 + qtr;
  for (int k = 0; k < nIter; k++) {
    int idx[2]; float w[2];
#pragma unroll
    for (int u = 0; u < 2; u++) {
      int ee = e + 4 * u;
      bool v = ee < e1;
      idx[u] = v ? e4[ee] : 0;
      w[u] = v ? 1.0f : 0.0f;
    }
    unsigned int d0 = *(const unsigned int*)&g8[(size_t)idx[0] * 64 + f0];
    unsigned int d1 = *(const unsigned int*)&g8[(size_t)idx[1] * 64 + f0];
    float r0[4], r1[4];
    fp8x4_to_f32(d0, r0); fp8x4_to_f32(d1, r1);
#pragma unroll
    for (int j = 0; j < 4; j++)
      acc[j] += r0[j] * w[0] + r1[j] * w[1];
    e += 8;
  }
#pragma unroll
  for (int j = 0; j < 4; j++) {
    acc[j] += __shfl_xor(acc[j], 16);
    acc[j] += __shfl_xor(acc[j], 32);
    acc[j] = di * acc[j] + bias[f0 + j];
  }
  // softmax over 64 features (16 lanes x 4 regs; all lanes hold full sums)
  float m = fmaxf(fmaxf(acc[0], acc[1]), fmaxf(acc[2], acc[3]));
#pragma unroll
  for (int off = 8; off > 0; off >>= 1) m = fmaxf(m, __shfl_xor(m, off));
  float ex[4], s = 0.0f;
#pragma unroll
  for (int j = 0; j < 4; j++) { ex[j] = __expf(acc[j] - m); s += ex[j]; }
#pragma unroll
  for (int off = 8; off > 0; off >>= 1) s += __shfl_xor(s, off);
  float rcs = 1.0f / s;
  float p[4], s2 = 0.0f;
#pragma unroll
  for (int j = 0; j < 4; j++) { p[j] = ex[j] * rcs; s2 += __expf(p[j]); }
#pragma unroll
  for (int off = 8; off > 0; off >>= 1) s2 += __shfl_xor(s2, off);
  float ls = __logf(s2);
  if (qtr == 0) {
    float4 o; o.x = p[0] - ls; o.y = p[1] - ls; o.z = p[2] - ls; o.w = p[3] - ls;
    *(float4*)&out[(size_t)i * 64 + f0] = o;
  }
}

// ---------- launch ----------
extern "C" void kernel_launch(void* const* d_in, const int* in_sizes, int n_in,
                              void* d_out, int out_size, void* d_ws, size_t ws_size,
                              hipStream_t stream) {
  const float* x    = (const float*)d_in[0];
  const int*   eidx = (const int*)d_in[1];
  const float* W1   = (const float*)d_in[2];
  const float* b1   = (const float*)d_in[3];
  const float* W2   = (const float*)d_in[4];
  const float* b2   = (const float*)d_in[5];
  const float* W3   = (const float*)d_in[6];
  const float* b3   = (const float*)d_in[7];
  float* out = (float*)d_out;

  const int E = in_sizes[1] / 2;            // 800000
  const int* src = eidx;
  const int* dst = eidx + E;

  char* p = (char*)d_ws;
  auto alloc = [&](size_t bytes) -> void* {
    void* r = (void*)p;
    p += (bytes + 255) & ~(size_t)255;
    return r;
  };
  unsigned char*  x8   = (unsigned char*)alloc((size_t)MPAD * 512);
  unsigned char*  g8   = (unsigned char*)alloc((size_t)MPAD * 256);  // gemm out (dinv-scaled) fp8
  unsigned char*  a8   = (unsigned char*)alloc((size_t)MPAD * 256);  // agg out fp8
  unsigned char*  g83  = (unsigned char*)alloc((size_t)MPAD * 64);
  unsigned char*  W1T8 = (unsigned char*)alloc((size_t)256 * 512);
  unsigned char*  W2T8 = (unsigned char*)alloc((size_t)256 * 256);
  unsigned char*  W3T8 = (unsigned char*)alloc((size_t)64 * 256);
  int*   cnt  = (int*)alloc((size_t)NN * 4);
  int*   rs   = (int*)alloc((size_t)(NN + 1) * 4);
  int*   rank = (int*)alloc((size_t)E * 4);
  float* dinv = (float*)alloc((size_t)MPAD * 4);
  int*   e4   = (int*)alloc((size_t)(E + 64) * 4);
  int*   bsum = (int*)alloc((size_t)SCAN_BLOCKS * 4);

  const int EB = (E + 255) / 256;  // 3125
  gcn_zero_k<<<SCAN_BLOCKS, 256, 0, stream>>>(cnt);
  gcn_prep_k<<<XB_BLOCKS + WB_BLOCKS, 256, 0, stream>>>(
      x, x8, W1, W2, W3, W1T8, W2T8, W3T8, dst, cnt, rank, E);
  gcn_scan_blocks_k<<<SCAN_BLOCKS, 256, 0, stream>>>(cnt, bsum, NN);
  gcn_scan_final_k<<<SCAN_BLOCKS, 256, 0, stream>>>(cnt, bsum, rs, dinv, NN, E);
  gcn_scatter_k<<<EB, 256, 0, stream>>>(src, dst, rank, rs, e4, E);

  const int MB = MPAD / 128;  // 391
  // layer 1
  gcn_gemm_f8_db_k<128, 4><<<dim3(MB, 2), 256, 0, stream>>>(x8, W1T8, dinv, g8, 512, 256);
  gcn_agg_relu_k<256><<<(NN + 3) / 4, 256, 0, stream>>>(g8, rs, e4, dinv, b1, a8, NN);
  // layer 2
  gcn_gemm_f8_db_k<128, 4><<<dim3(MB, 2), 256, 0, stream>>>(a8, W2T8, dinv, g8, 256, 256);
  gcn_agg_relu_k<256><<<(NN + 3) / 4, 256, 0, stream>>>(g8, rs, e4, dinv, b2, a8, NN);
  // layer 3 + fused softmax/log_softmax
  gcn_gemm_f8_s_k<64, 2><<<dim3(MB, 1), 256, 0, stream>>>(a8, W3T8, dinv, g83, 256, 64);
  gcn_agg_final_k<<<(NN + 3) / 4, 256, 0, stream>>>(g83, rs, e4, dinv, b3, out, NN);

  (void)n_in; (void)out_size; (void)ws_size;
}